// Round 1
// baseline (925.158 us; speedup 1.0000x reference)
//
#include <hip/hip_runtime.h>
#include <math.h>

// Problem constants (B=1)
#define S_LEN 2048
#define HID   1024
#define NH    16
#define HD    64
#define NM    128
#define CAUG  192   // 64 (q/k part) + 128 (phi part)

constexpr float ALPHA = 0.9f;

// ---------------------------------------------------------------------------
// GEMM: C = A @ W^T + bias.  A:(2048x1024), W:(1024x1024) row-major [n][k].
// 128x128 tile, BK=16, 256 threads, 8x8 micro-tile (split 4+4 for bank spread)
// ---------------------------------------------------------------------------
__global__ __launch_bounds__(256)
void gemm_bt(const float* __restrict__ A,
             const float* __restrict__ W0, const float* __restrict__ b0, float* __restrict__ C0,
             const float* __restrict__ W1, const float* __restrict__ b1, float* __restrict__ C1,
             const float* __restrict__ W2, const float* __restrict__ b2, float* __restrict__ C2)
{
    const float* W; const float* bias; float* C;
    if (blockIdx.z == 0)      { W = W0; bias = b0; C = C0; }
    else if (blockIdx.z == 1) { W = W1; bias = b1; C = C1; }
    else                      { W = W2; bias = b2; C = C2; }

    __shared__ float As[16][128];
    __shared__ float Bs[16][128];

    const int tid = threadIdx.x;
    const int tx = tid & 15;
    const int ty = tid >> 4;
    const int rowBase = blockIdx.y * 128;
    const int colBase = blockIdx.x * 128;

    float acc[8][8];
#pragma unroll
    for (int i = 0; i < 8; ++i)
#pragma unroll
        for (int j = 0; j < 8; ++j) acc[i][j] = 0.f;

    const int lr = tid >> 1;          // 0..127
    const int lk = (tid & 1) * 8;     // 0 or 8
    const float* Arow = A + (size_t)(rowBase + lr) * HID + lk;
    const float* Wrow = W + (size_t)(colBase + lr) * HID + lk;

    for (int kc = 0; kc < HID; kc += 16) {
        float4 a0 = *(const float4*)(Arow + kc);
        float4 a1 = *(const float4*)(Arow + kc + 4);
        float4 w0 = *(const float4*)(Wrow + kc);
        float4 w1 = *(const float4*)(Wrow + kc + 4);
        __syncthreads();   // previous iter done reading LDS
        As[lk+0][lr]=a0.x; As[lk+1][lr]=a0.y; As[lk+2][lr]=a0.z; As[lk+3][lr]=a0.w;
        As[lk+4][lr]=a1.x; As[lk+5][lr]=a1.y; As[lk+6][lr]=a1.z; As[lk+7][lr]=a1.w;
        Bs[lk+0][lr]=w0.x; Bs[lk+1][lr]=w0.y; Bs[lk+2][lr]=w0.z; Bs[lk+3][lr]=w0.w;
        Bs[lk+4][lr]=w1.x; Bs[lk+5][lr]=w1.y; Bs[lk+6][lr]=w1.z; Bs[lk+7][lr]=w1.w;
        __syncthreads();
#pragma unroll
        for (int kk = 0; kk < 16; ++kk) {
            float4 aL = *(const float4*)&As[kk][ty*4];
            float4 aH = *(const float4*)&As[kk][64 + ty*4];
            float4 bL = *(const float4*)&Bs[kk][tx*4];
            float4 bH = *(const float4*)&Bs[kk][64 + tx*4];
            float av[8] = {aL.x,aL.y,aL.z,aL.w,aH.x,aH.y,aH.z,aH.w};
            float bv[8] = {bL.x,bL.y,bL.z,bL.w,bH.x,bH.y,bH.z,bH.w};
#pragma unroll
            for (int i = 0; i < 8; ++i)
#pragma unroll
                for (int j = 0; j < 8; ++j)
                    acc[i][j] = fmaf(av[i], bv[j], acc[i][j]);
        }
    }

    float4 bL = *(const float4*)(bias + colBase + tx*4);
    float4 bH = *(const float4*)(bias + colBase + 64 + tx*4);
    float bb[8] = {bL.x,bL.y,bL.z,bL.w,bH.x,bH.y,bH.z,bH.w};
#pragma unroll
    for (int i = 0; i < 8; ++i) {
        int r = rowBase + ((i < 4) ? (ty*4 + i) : (64 + ty*4 + (i - 4)));
        float4 lo = make_float4(acc[i][0]+bb[0], acc[i][1]+bb[1], acc[i][2]+bb[2], acc[i][3]+bb[3]);
        float4 hi = make_float4(acc[i][4]+bb[4], acc[i][5]+bb[5], acc[i][6]+bb[6], acc[i][7]+bb[7]);
        *(float4*)(C + (size_t)r*HID + colBase + tx*4)      = lo;
        *(float4*)(C + (size_t)r*HID + colBase + 64 + tx*4) = hi;
    }
}

// ---------------------------------------------------------------------------
// phi kernel: per row (h,s) of q or k:
//   xn = x/(||x||+1e-6);  proj = xn @ omega[h] + rff_b[h];  phi = 0.125*cos(proj)
//   phin = phi/(||phi||+1e-6)
// Writes augmented rows:
//   Qa[h][s] = [ (alpha/8)*q , ((1-alpha)/8)*phin(q) ]     (192 floats)
//   Ka[h][s] = [ k           ,  phin(k)              ]
// Block = 256 thr = 4 waves; block handles 16 rows of one (src,h); omega[h] in LDS.
// ---------------------------------------------------------------------------
__global__ __launch_bounds__(256)
void phi_kernel(const float* __restrict__ qbuf, const float* __restrict__ kbuf,
                const float* __restrict__ omega, const float* __restrict__ rffb,
                float* __restrict__ Qa, float* __restrict__ Ka)
{
    __shared__ float ws_om[HD * NM];   // 32 KiB
    __shared__ float ws_b[NM];

    const int bid = blockIdx.x;
    const int base_row = bid * 16;              // flattened (src,h,s), s fastest
    const int src = base_row / (NH * S_LEN);
    const int rem = base_row % (NH * S_LEN);
    const int h  = rem / S_LEN;
    const int s0 = rem % S_LEN;

    const float* X  = src ? kbuf : qbuf;
    float* Out      = src ? Ka : Qa;
    const float fq   = src ? 1.0f : (ALPHA * 0.125f);
    const float fphi = src ? 1.0f : ((1.0f - ALPHA) * 0.125f);

    for (int i = threadIdx.x; i < HD * NM; i += 256) ws_om[i] = omega[h * HD * NM + i];
    if (threadIdx.x < NM) ws_b[threadIdx.x] = rffb[h * NM + threadIdx.x];
    __syncthreads();

    const int wave = threadIdx.x >> 6;
    const int lane = threadIdx.x & 63;

    for (int rr = 0; rr < 4; ++rr) {
        const int s = s0 + wave * 4 + rr;
        const float x = X[(size_t)s * HID + h * HD + lane];
        float ss = x * x;
#pragma unroll
        for (int off = 32; off > 0; off >>= 1) ss += __shfl_xor(ss, off);
        const float xn = x / (sqrtf(ss) + 1e-6f);

        float acc0 = 0.f, acc1 = 0.f;
#pragma unroll 8
        for (int d = 0; d < 64; ++d) {
            const float xv = __shfl(xn, d);
            acc0 = fmaf(xv, ws_om[d * NM + lane],      acc0);
            acc1 = fmaf(xv, ws_om[d * NM + 64 + lane], acc1);
        }
        const float p0 = acc0 + ws_b[lane];
        const float p1 = acc1 + ws_b[64 + lane];
        const float c = 0.125f;                 // sqrt(2/128)
        const float ph0 = c * __cosf(p0);
        const float ph1 = c * __cosf(p1);
        float n2 = ph0 * ph0 + ph1 * ph1;
#pragma unroll
        for (int off = 32; off > 0; off >>= 1) n2 += __shfl_xor(n2, off);
        const float inv = 1.0f / (sqrtf(n2) + 1e-6f);

        float* row = Out + ((size_t)h * S_LEN + s) * CAUG;
        row[lane]       = fq * x;
        row[64 + lane]  = fphi * ph0 * inv;
        row[128 + lane] = fphi * ph1 * inv;
    }
}

// ---------------------------------------------------------------------------
// Flash attention, fp32.  scores = Qa . Ka (C=192), online softmax, O += P.V
// Block: 256 thr, Q-tile 64 rows, K-chunk 64, c staged in 3 slabs of 64.
// Per-thread 4x4 register tiles for both score and PV phases.
// ---------------------------------------------------------------------------
__global__ __launch_bounds__(256)
void flash_kernel(const float* __restrict__ Qa, const float* __restrict__ Ka,
                  const float* __restrict__ vbuf, const float* __restrict__ mask,
                  float* __restrict__ ctx)
{
    __shared__ float Qc[64][68];   // transposed c-slab: Qc[c][i]
    __shared__ float KV[64][68];   // Kc[c][j] during scores; V[j][d] during PV
    __shared__ float Ss[64][68];   // probabilities
    __shared__ float mrow[64], lrow[64], srow[64];

    const int h  = blockIdx.y;
    const int qt = blockIdx.x;
    const int tid = threadIdx.x;
    const int tx = tid & 15;
    const int ty = tid >> 4;

    const float* Qbase = Qa + ((size_t)h * S_LEN + qt * 64) * CAUG;
    const float* Kbase = Ka + (size_t)h * S_LEN * CAUG;

    if (tid < 64) { mrow[tid] = -1e30f; lrow[tid] = 0.f; }

    float oacc[4][4];
#pragma unroll
    for (int i = 0; i < 4; ++i)
#pragma unroll
        for (int j = 0; j < 4; ++j) oacc[i][j] = 0.f;

    const int si  = tid >> 2;         // 0..63 staging row
    const int sc4 = (tid & 3) * 16;   // staging col base

    for (int kt = 0; kt < S_LEN / 64; ++kt) {
        float sacc[4][4];
#pragma unroll
        for (int i = 0; i < 4; ++i)
#pragma unroll
            for (int j = 0; j < 4; ++j) sacc[i][j] = 0.f;

        for (int cch = 0; cch < 3; ++cch) {
            const float* qsrc = Qbase + (size_t)si * CAUG + cch * 64 + sc4;
            const float* ksrc = Kbase + (size_t)(kt * 64 + si) * CAUG + cch * 64 + sc4;
            float4 qv0 = *(const float4*)(qsrc);
            float4 qv1 = *(const float4*)(qsrc + 4);
            float4 qv2 = *(const float4*)(qsrc + 8);
            float4 qv3 = *(const float4*)(qsrc + 12);
            float4 kv0 = *(const float4*)(ksrc);
            float4 kv1 = *(const float4*)(ksrc + 4);
            float4 kv2 = *(const float4*)(ksrc + 8);
            float4 kv3 = *(const float4*)(ksrc + 12);
            __syncthreads();   // previous readers of Qc/KV done
            Qc[sc4+ 0][si]=qv0.x; Qc[sc4+ 1][si]=qv0.y; Qc[sc4+ 2][si]=qv0.z; Qc[sc4+ 3][si]=qv0.w;
            Qc[sc4+ 4][si]=qv1.x; Qc[sc4+ 5][si]=qv1.y; Qc[sc4+ 6][si]=qv1.z; Qc[sc4+ 7][si]=qv1.w;
            Qc[sc4+ 8][si]=qv2.x; Qc[sc4+ 9][si]=qv2.y; Qc[sc4+10][si]=qv2.z; Qc[sc4+11][si]=qv2.w;
            Qc[sc4+12][si]=qv3.x; Qc[sc4+13][si]=qv3.y; Qc[sc4+14][si]=qv3.z; Qc[sc4+15][si]=qv3.w;
            KV[sc4+ 0][si]=kv0.x; KV[sc4+ 1][si]=kv0.y; KV[sc4+ 2][si]=kv0.z; KV[sc4+ 3][si]=kv0.w;
            KV[sc4+ 4][si]=kv1.x; KV[sc4+ 5][si]=kv1.y; KV[sc4+ 6][si]=kv1.z; KV[sc4+ 7][si]=kv1.w;
            KV[sc4+ 8][si]=kv2.x; KV[sc4+ 9][si]=kv2.y; KV[sc4+10][si]=kv2.z; KV[sc4+11][si]=kv2.w;
            KV[sc4+12][si]=kv3.x; KV[sc4+13][si]=kv3.y; KV[sc4+14][si]=kv3.z; KV[sc4+15][si]=kv3.w;
            __syncthreads();
#pragma unroll 4
            for (int c = 0; c < 64; ++c) {
                float4 qq = *(const float4*)&Qc[c][ty*4];
                float4 kk = *(const float4*)&KV[c][tx*4];
                float qa_[4] = {qq.x, qq.y, qq.z, qq.w};
                float kb_[4] = {kk.x, kk.y, kk.z, kk.w};
#pragma unroll
                for (int i = 0; i < 4; ++i)
#pragma unroll
                    for (int j = 0; j < 4; ++j)
                        sacc[i][j] = fmaf(qa_[i], kb_[j], sacc[i][j]);
            }
        }

        __syncthreads();   // score reads of KV done -> stage V into KV
        {
            const float* vsrc = vbuf + (size_t)(kt * 64 + si) * HID + h * HD + sc4;
            float4 vv0 = *(const float4*)(vsrc);
            float4 vv1 = *(const float4*)(vsrc + 4);
            float4 vv2 = *(const float4*)(vsrc + 8);
            float4 vv3 = *(const float4*)(vsrc + 12);
            *(float4*)&KV[si][sc4 + 0]  = vv0;
            *(float4*)&KV[si][sc4 + 4]  = vv1;
            *(float4*)&KV[si][sc4 + 8]  = vv2;
            *(float4*)&KV[si][sc4 + 12] = vv3;
        }

        // online softmax (row groups = 16 contiguous lanes of one wave)
        {
            float4 mv = *(const float4*)(mask + kt * 64 + tx * 4);
            float mvals[4] = {mv.x * -10000.0f, mv.y * -10000.0f, mv.z * -10000.0f, mv.w * -10000.0f};
#pragma unroll
            for (int i = 0; i < 4; ++i) {
                const int r = ty * 4 + i;
                float s0 = sacc[i][0] + mvals[0];
                float s1 = sacc[i][1] + mvals[1];
                float s2 = sacc[i][2] + mvals[2];
                float s3 = sacc[i][3] + mvals[3];
                float mx = fmaxf(fmaxf(s0, s1), fmaxf(s2, s3));
#pragma unroll
                for (int off = 1; off < 16; off <<= 1)
                    mx = fmaxf(mx, __shfl_xor(mx, off));
                const float mold = mrow[r];
                const float mnew = fmaxf(mold, mx);
                const float p0 = __expf(s0 - mnew);
                const float p1 = __expf(s1 - mnew);
                const float p2 = __expf(s2 - mnew);
                const float p3 = __expf(s3 - mnew);
                float ps = p0 + p1 + p2 + p3;
#pragma unroll
                for (int off = 1; off < 16; off <<= 1)
                    ps += __shfl_xor(ps, off);
                const float scl = __expf(mold - mnew);
                if (tx == 0) { mrow[r] = mnew; lrow[r] = lrow[r] * scl + ps; srow[r] = scl; }
                *(float4*)&Ss[r][tx*4] = make_float4(p0, p1, p2, p3);
            }
        }
        __syncthreads();   // Ss, srow, V ready

        // PV: rows ty*4+i, d-cols tx*4..tx*4+3
#pragma unroll
        for (int i = 0; i < 4; ++i) {
            const float scl = srow[ty*4 + i];
            oacc[i][0] *= scl; oacc[i][1] *= scl; oacc[i][2] *= scl; oacc[i][3] *= scl;
        }
#pragma unroll 4
        for (int j = 0; j < 64; ++j) {
            float4 vv = *(const float4*)&KV[j][tx*4];
#pragma unroll
            for (int i = 0; i < 4; ++i) {
                const float p = Ss[ty*4 + i][j];
                oacc[i][0] = fmaf(p, vv.x, oacc[i][0]);
                oacc[i][1] = fmaf(p, vv.y, oacc[i][1]);
                oacc[i][2] = fmaf(p, vv.z, oacc[i][2]);
                oacc[i][3] = fmaf(p, vv.w, oacc[i][3]);
            }
        }
    }
    __syncthreads();

#pragma unroll
    for (int i = 0; i < 4; ++i) {
        const int r = ty * 4 + i;
        const float inv = 1.0f / lrow[r];
        float4 o = make_float4(oacc[i][0]*inv, oacc[i][1]*inv, oacc[i][2]*inv, oacc[i][3]*inv);
        *(float4*)(ctx + (size_t)(qt * 64 + r) * HID + h * HD + tx * 4) = o;
    }
}

// ---------------------------------------------------------------------------
extern "C" void kernel_launch(void* const* d_in, const int* in_sizes, int n_in,
                              void* d_out, int out_size, void* d_ws, size_t ws_size,
                              hipStream_t stream)
{
    const float* hs    = (const float*)d_in[0];
    const float* mask  = (const float*)d_in[1];
    const float* Wq    = (const float*)d_in[2];
    const float* bq    = (const float*)d_in[3];
    const float* Wk    = (const float*)d_in[4];
    const float* bk    = (const float*)d_in[5];
    const float* Wv    = (const float*)d_in[6];
    const float* bv    = (const float*)d_in[7];
    const float* Wo    = (const float*)d_in[8];
    const float* bo    = (const float*)d_in[9];
    const float* omega = (const float*)d_in[10];
    const float* rffb  = (const float*)d_in[11];
    float* out = (float*)d_out;
    float* ws  = (float*)d_ws;

    const size_t SH  = (size_t)S_LEN * HID;          // 2,097,152
    const size_t AUG = (size_t)NH * S_LEN * CAUG;    // 6,291,456
    float* qb  = ws;
    float* kb  = ws + SH;
    float* vb  = ws + 2 * SH;
    float* QaB = ws + 3 * SH;
    float* KaB = ws + 3 * SH + AUG;
    float* ctx = qb;   // q dead after phi; reuse as context buffer
    // total ws use: (3*SH + 2*AUG)*4 B ~= 75.5 MB

    gemm_bt<<<dim3(8, 16, 3), 256, 0, stream>>>(hs, Wq, bq, qb, Wk, bk, kb, Wv, bv, vb);
    phi_kernel<<<dim3(4096), 256, 0, stream>>>(qb, kb, omega, rffb, QaB, KaB);
    flash_kernel<<<dim3(32, 16), 256, 0, stream>>>(QaB, KaB, vb, mask, ctx);
    gemm_bt<<<dim3(8, 16, 1), 256, 0, stream>>>(ctx, Wo, bo, out, Wo, bo, out, Wo, bo, out);
}

// Round 2
// 234.355 us; speedup vs baseline: 3.9477x; 3.9477x over previous
//
#include <hip/hip_runtime.h>
#include <math.h>

#define S_LEN 2048
#define HID   1024
#define NH    16
#define HD    64
#define NM    128
#define CAUG  192
#define KC    64
#define NT    (S_LEN / KC)

constexpr float ALPHA = 0.9f;

typedef __attribute__((ext_vector_type(8))) short bf16x8;
typedef __attribute__((ext_vector_type(4))) short bf16x4;
typedef __attribute__((ext_vector_type(4))) float f32x4;
typedef __attribute__((ext_vector_type(4))) int   int4v;

#define MFMA(a,b,c) __builtin_amdgcn_mfma_f32_16x16x32_bf16(a,b,c,0,0,0)

static __device__ inline short f2bf(float f) {
    unsigned u = __float_as_uint(f);
    u += 0x7fffu + ((u >> 16) & 1u);      // RNE
    return (short)(u >> 16);
}
static __device__ inline float bf2f(short s) {
    return __uint_as_float(((unsigned)(unsigned short)s) << 16);
}

// ---------------------------------------------------------------------------
// fp32 -> bf16 conversion: hs (2M elems) + Wq/Wk/Wv/Wo (1M each), float4-wide
// ---------------------------------------------------------------------------
__global__ __launch_bounds__(256)
void conv_kernel(const float* __restrict__ hs,
                 const float* __restrict__ Wq, const float* __restrict__ Wk,
                 const float* __restrict__ Wv, const float* __restrict__ Wo,
                 short* __restrict__ hsb, short* __restrict__ wqb, short* __restrict__ wkb,
                 short* __restrict__ wvb, short* __restrict__ wob)
{
    int i = blockIdx.x * 256 + threadIdx.x;           // f4-unit index, 1,572,864 total
    if (i >= 1572864) return;
    const float* src; short* dst; int off;
    if (i < 524288) { src = hs; dst = hsb; off = i; }
    else {
        int j = i - 524288;
        int r = j >> 18;              // 0..3
        off = j & 262143;
        src = (r == 0) ? Wq : (r == 1) ? Wk : (r == 2) ? Wv : Wo;
        dst = (r == 0) ? wqb : (r == 1) ? wkb : (r == 2) ? wvb : wob;
    }
    float4 v = ((const float4*)src)[off];
    bf16x4 o; o[0] = f2bf(v.x); o[1] = f2bf(v.y); o[2] = f2bf(v.z); o[3] = f2bf(v.w);
    ((bf16x4*)dst)[off] = o;
}

// ---------------------------------------------------------------------------
// bf16 MFMA GEMM: C = A(2048x1024) @ W(1024x1024)^T + bias
// 128x128 tile, BK=32, 4 waves (2x2), 4x4 frags/wave, reg-staged padded LDS.
// mode 0: C bf16 [m][1024];  mode 1: C bf16 transposed [n][Mrows];  mode 2: C f32
// ---------------------------------------------------------------------------
__global__ __launch_bounds__(256)
void gemm_mfma(const short* __restrict__ A,
               const short* __restrict__ W0, const float* __restrict__ b0, void* C0,
               const short* __restrict__ W1, const float* __restrict__ b1, void* C1,
               const short* __restrict__ W2, const float* __restrict__ b2, void* C2,
               int m0_, int m1_, int m2_, int Mrows)
{
    const short* W; const float* bias; void* C; int mode;
    if (blockIdx.z == 0)      { W = W0; bias = b0; C = C0; mode = m0_; }
    else if (blockIdx.z == 1) { W = W1; bias = b1; C = C1; mode = m1_; }
    else                      { W = W2; bias = b2; C = C2; mode = m2_; }

    __shared__ short As[128][40];   // 32 cols + 4 pad -> 80B rows (bank spread)
    __shared__ short Bs[128][40];

    const int tid = threadIdx.x;
    const int wave = tid >> 6, lane = tid & 63;
    const int l15 = lane & 15, l4 = lane >> 4;
    const int wm = wave >> 1, wn = wave & 1;
    const int m0 = blockIdx.y * 128, n0 = blockIdx.x * 128;

    const int srow = (tid >> 2);          // + it*64
    const int scol = (tid & 3) * 16;      // byte col within 64B row

    f32x4 acc[4][4];
#pragma unroll
    for (int i = 0; i < 4; ++i)
#pragma unroll
        for (int j = 0; j < 4; ++j) acc[i][j] = (f32x4){0.f,0.f,0.f,0.f};

    int4v apre[2], bpre[2];
#pragma unroll
    for (int it = 0; it < 2; ++it) {
        apre[it] = *(const int4v*)((const char*)A + (size_t)(m0 + srow + it*64) * 2048 + scol);
        bpre[it] = *(const int4v*)((const char*)W + (size_t)(n0 + srow + it*64) * 2048 + scol);
    }

    for (int ks = 0; ks < 32; ++ks) {
        __syncthreads();
#pragma unroll
        for (int it = 0; it < 2; ++it) {
            *(int4v*)((char*)&As[0][0] + (srow + it*64) * 80 + scol) = apre[it];
            *(int4v*)((char*)&Bs[0][0] + (srow + it*64) * 80 + scol) = bpre[it];
        }
        __syncthreads();
        if (ks + 1 < 32) {
            const int kb = (ks + 1) * 64;
#pragma unroll
            for (int it = 0; it < 2; ++it) {
                apre[it] = *(const int4v*)((const char*)A + (size_t)(m0 + srow + it*64) * 2048 + kb + scol);
                bpre[it] = *(const int4v*)((const char*)W + (size_t)(n0 + srow + it*64) * 2048 + kb + scol);
            }
        }
        bf16x8 af[4], bf[4];
#pragma unroll
        for (int mi = 0; mi < 4; ++mi)
            af[mi] = *(const bf16x8*)((const char*)&As[0][0] + (wm*64 + mi*16 + l15) * 80 + l4*16);
#pragma unroll
        for (int nj = 0; nj < 4; ++nj)
            bf[nj] = *(const bf16x8*)((const char*)&Bs[0][0] + (wn*64 + nj*16 + l15) * 80 + l4*16);
#pragma unroll
        for (int mi = 0; mi < 4; ++mi)
#pragma unroll
            for (int nj = 0; nj < 4; ++nj)
                acc[mi][nj] = MFMA(af[mi], bf[nj], acc[mi][nj]);
    }

#pragma unroll
    for (int nj = 0; nj < 4; ++nj) {
        const int nglob = n0 + wn*64 + nj*16 + l15;
        const float bn = bias[nglob];
#pragma unroll
        for (int mi = 0; mi < 4; ++mi) {
            const int mbase = m0 + wm*64 + mi*16 + l4*4;
            if (mode == 0) {
#pragma unroll
                for (int r = 0; r < 4; ++r)
                    ((short*)C)[(size_t)(mbase + r) * 1024 + nglob] = f2bf(acc[mi][nj][r] + bn);
            } else if (mode == 1) {
                bf16x4 pk;
#pragma unroll
                for (int r = 0; r < 4; ++r) pk[r] = f2bf(acc[mi][nj][r] + bn);
                *(bf16x4*)((short*)C + (size_t)nglob * Mrows + mbase) = pk;
            } else {
#pragma unroll
                for (int r = 0; r < 4; ++r)
                    ((float*)C)[(size_t)(mbase + r) * 1024 + nglob] = acc[mi][nj][r] + bn;
            }
        }
    }
}

// ---------------------------------------------------------------------------
// phi kernel (VALU): per row of q/k -> augmented bf16 rows
//   Qa[h][s] = [ (a/8)*q , ((1-a)/8)*phin(q) ],  Ka[h][s] = [ k , phin(k) ]
// ---------------------------------------------------------------------------
__global__ __launch_bounds__(256)
void phi_kernel(const short* __restrict__ qbuf, const short* __restrict__ kbuf,
                const float* __restrict__ omega, const float* __restrict__ rffb,
                short* __restrict__ Qa, short* __restrict__ Ka)
{
    __shared__ float ws_om[HD * NM];
    __shared__ float ws_b[NM];

    const int bid = blockIdx.x;
    const int base_row = bid * 16;
    const int src = base_row / (NH * S_LEN);
    const int rem = base_row % (NH * S_LEN);
    const int h  = rem / S_LEN;
    const int s0 = rem % S_LEN;

    const short* X = src ? kbuf : qbuf;
    short* Out     = src ? Ka : Qa;
    const float fq   = src ? 1.0f : (ALPHA * 0.125f);
    const float fphi = src ? 1.0f : ((1.0f - ALPHA) * 0.125f);

    for (int i = threadIdx.x; i < HD * NM; i += 256) ws_om[i] = omega[h * HD * NM + i];
    if (threadIdx.x < NM) ws_b[threadIdx.x] = rffb[h * NM + threadIdx.x];
    __syncthreads();

    const int wave = threadIdx.x >> 6;
    const int lane = threadIdx.x & 63;

    for (int rr = 0; rr < 4; ++rr) {
        const int s = s0 + wave * 4 + rr;
        const float x = bf2f(X[(size_t)s * HID + h * HD + lane]);
        float ss = x * x;
#pragma unroll
        for (int off = 32; off > 0; off >>= 1) ss += __shfl_xor(ss, off);
        const float xn = x / (sqrtf(ss) + 1e-6f);

        float acc0 = 0.f, acc1 = 0.f;
#pragma unroll 8
        for (int d = 0; d < 64; ++d) {
            const float xv = __shfl(xn, d);
            acc0 = fmaf(xv, ws_om[d * NM + lane],      acc0);
            acc1 = fmaf(xv, ws_om[d * NM + 64 + lane], acc1);
        }
        const float p0 = acc0 + ws_b[lane];
        const float p1 = acc1 + ws_b[64 + lane];
        const float ph0 = 0.125f * __cosf(p0);
        const float ph1 = 0.125f * __cosf(p1);
        float n2 = ph0 * ph0 + ph1 * ph1;
#pragma unroll
        for (int off = 32; off > 0; off >>= 1) n2 += __shfl_xor(n2, off);
        const float inv = 1.0f / (sqrtf(n2) + 1e-6f);

        short* row = Out + ((size_t)h * S_LEN + s) * CAUG;
        row[lane]       = f2bf(fq * x);
        row[64 + lane]  = f2bf(fphi * ph0 * inv);
        row[128 + lane] = f2bf(fphi * ph1 * inv);
    }
}

// ---------------------------------------------------------------------------
// MFMA flash attention. Swapped orientation:
//   S^T[kpos][q] = K'(64x192) . Q'^T  (A=K' rows from LDS, B=Q' rows from regs)
//   softmax along kpos = frag rows (+shfl 16/32), P written row-major [q][kpos]
//   O^T[d][q]   = V^T(64x64) . P^T    (A=Vt LDS rows, B=P LDS rows)
// 4 waves x 32 q-rows, per-wave-private P slab (no barrier in softmax/PV path).
// ---------------------------------------------------------------------------
__global__ __launch_bounds__(256)
void flash_mfma(const short* __restrict__ Qa, const short* __restrict__ Ka,
                const short* __restrict__ vt, const float* __restrict__ mask,
                short* __restrict__ ctxb)
{
    __shared__ short Ks[64][200];      // 192 + 8 pad -> 400B rows
    __shared__ short Vt[64][72];       // 64 + 8 pad  -> 144B rows
    __shared__ short Pl[4][32][72];    // per-wave private

    const int tid = threadIdx.x;
    const int wave = tid >> 6, lane = tid & 63;
    const int l15 = lane & 15, l4 = lane >> 4;
    const int h = blockIdx.y;
    const int q0 = blockIdx.x * 128 + wave * 32;

    // Q' fragments, resident whole kernel
    bf16x8 qf[2][6];
#pragma unroll
    for (int qj = 0; qj < 2; ++qj)
#pragma unroll
        for (int cs = 0; cs < 6; ++cs)
            qf[qj][cs] = *(const bf16x8*)(Qa + ((size_t)h * 2048 + q0 + qj*16 + l15) * CAUG + cs*32 + l4*8);

    f32x4 oacc[4][2];
#pragma unroll
    for (int di = 0; di < 4; ++di)
#pragma unroll
        for (int qj = 0; qj < 2; ++qj) oacc[di][qj] = (f32x4){0.f,0.f,0.f,0.f};
    float mreg[2] = {-1e30f, -1e30f}, lreg[2] = {0.f, 0.f};

    // staging geometry (bytes): K chunk 64x384B, V chunk 64x128B
    int kr[6], kcb[6], vr[2], vcb[2];
#pragma unroll
    for (int it = 0; it < 6; ++it) { int f = tid*16 + it*4096; kr[it] = f/384; kcb[it] = f%384; }
#pragma unroll
    for (int it = 0; it < 2; ++it) { int f = tid*16 + it*4096; vr[it] = f/128; vcb[it] = f%128; }

    const char* Kg = (const char*)(Ka + (size_t)h * 2048 * CAUG);
    const char* Vg = (const char*)(vt + (size_t)h * 64 * 2048);

    int4v kpre[6], vpre[2];
#pragma unroll
    for (int it = 0; it < 6; ++it) kpre[it] = *(const int4v*)(Kg + (size_t)kr[it]*384 + kcb[it]);
#pragma unroll
    for (int it = 0; it < 2; ++it) vpre[it] = *(const int4v*)(Vg + (size_t)vr[it]*4096 + vcb[it]);

    for (int kt = 0; kt < NT; ++kt) {
        __syncthreads();                    // readers of previous chunk done
#pragma unroll
        for (int it = 0; it < 6; ++it)
            *(int4v*)((char*)&Ks[0][0] + kr[it]*400 + kcb[it]) = kpre[it];
#pragma unroll
        for (int it = 0; it < 2; ++it)
            *(int4v*)((char*)&Vt[0][0] + vr[it]*144 + vcb[it]) = vpre[it];
        __syncthreads();
        if (kt + 1 < NT) {
            const size_t ko = (size_t)(kt + 1) * 64 * 384;
            const size_t vo = (size_t)(kt + 1) * 128;
#pragma unroll
            for (int it = 0; it < 6; ++it) kpre[it] = *(const int4v*)(Kg + ko + (size_t)kr[it]*384 + kcb[it]);
#pragma unroll
            for (int it = 0; it < 2; ++it) vpre[it] = *(const int4v*)(Vg + (size_t)vr[it]*4096 + vo + vcb[it]);
        }

        // ---- scores S^T (64 kpos x 32 q) ----
        f32x4 sacc[4][2];
#pragma unroll
        for (int fi = 0; fi < 4; ++fi)
#pragma unroll
            for (int qj = 0; qj < 2; ++qj) sacc[fi][qj] = (f32x4){0.f,0.f,0.f,0.f};
#pragma unroll
        for (int cs = 0; cs < 6; ++cs) {
            bf16x8 ka[4];
#pragma unroll
            for (int fi = 0; fi < 4; ++fi)
                ka[fi] = *(const bf16x8*)((const char*)&Ks[0][0] + (fi*16 + l15)*400 + cs*64 + l4*16);
#pragma unroll
            for (int fi = 0; fi < 4; ++fi)
#pragma unroll
                for (int qj = 0; qj < 2; ++qj)
                    sacc[fi][qj] = MFMA(ka[fi], qf[qj][cs], sacc[fi][qj]);
        }
        // mask (broadcast over q; depends on kpos = frag row)
#pragma unroll
        for (int fi = 0; fi < 4; ++fi) {
            float4 mk = *(const float4*)&mask[kt*64 + fi*16 + l4*4];
            float mv[4] = {mk.x * -10000.f, mk.y * -10000.f, mk.z * -10000.f, mk.w * -10000.f};
#pragma unroll
            for (int qj = 0; qj < 2; ++qj)
#pragma unroll
                for (int r = 0; r < 4; ++r) sacc[fi][qj][r] += mv[r];
        }
        // ---- online softmax per q-column ----
#pragma unroll
        for (int qj = 0; qj < 2; ++qj) {
            float pm = -1e30f;
#pragma unroll
            for (int fi = 0; fi < 4; ++fi)
#pragma unroll
                for (int r = 0; r < 4; ++r) pm = fmaxf(pm, sacc[fi][qj][r]);
            pm = fmaxf(pm, __shfl_xor(pm, 16));
            pm = fmaxf(pm, __shfl_xor(pm, 32));
            const float mnew = fmaxf(mreg[qj], pm);
            const float sc = __expf(mreg[qj] - mnew);
            mreg[qj] = mnew;
            float ps = 0.f;
#pragma unroll
            for (int fi = 0; fi < 4; ++fi)
#pragma unroll
                for (int r = 0; r < 4; ++r) {
                    float p = __expf(sacc[fi][qj][r] - mnew);
                    sacc[fi][qj][r] = p;
                    ps += p;
                }
            ps += __shfl_xor(ps, 16);
            ps += __shfl_xor(ps, 32);
            lreg[qj] = lreg[qj] * sc + ps;
#pragma unroll
            for (int di = 0; di < 4; ++di)
#pragma unroll
                for (int r = 0; r < 4; ++r) oacc[di][qj][r] *= sc;
#pragma unroll
            for (int fi = 0; fi < 4; ++fi) {
                bf16x4 pk;
#pragma unroll
                for (int r = 0; r < 4; ++r) pk[r] = f2bf(sacc[fi][qj][r]);
                *(bf16x4*)(&Pl[wave][qj*16 + l15][fi*16 + l4*4]) = pk;
            }
        }
        // ---- PV: O^T += V^T . P^T ----
#pragma unroll
        for (int cs2 = 0; cs2 < 2; ++cs2) {
            bf16x8 va[4], pb[2];
#pragma unroll
            for (int di = 0; di < 4; ++di)
                va[di] = *(const bf16x8*)((const char*)&Vt[0][0] + (di*16 + l15)*144 + cs2*64 + l4*16);
#pragma unroll
            for (int qj = 0; qj < 2; ++qj)
                pb[qj] = *(const bf16x8*)((const char*)&Pl[wave][0][0] + (qj*16 + l15)*144 + cs2*64 + l4*16);
#pragma unroll
            for (int di = 0; di < 4; ++di)
#pragma unroll
                for (int qj = 0; qj < 2; ++qj)
                    oacc[di][qj] = MFMA(va[di], pb[qj], oacc[di][qj]);
        }
    }

    // epilogue: ctx bf16 [s][1024]
#pragma unroll
    for (int qj = 0; qj < 2; ++qj) {
        const float inv = 1.0f / lreg[qj];
        const int s = q0 + qj*16 + l15;
#pragma unroll
        for (int di = 0; di < 4; ++di) {
            bf16x4 o;
#pragma unroll
            for (int r = 0; r < 4; ++r) o[r] = f2bf(oacc[di][qj][r] * inv);
            *(bf16x4*)(ctxb + (size_t)s * HID + h*64 + di*16 + l4*4) = o;
        }
    }
}

// ---------------------------------------------------------------------------
extern "C" void kernel_launch(void* const* d_in, const int* in_sizes, int n_in,
                              void* d_out, int out_size, void* d_ws, size_t ws_size,
                              hipStream_t stream)
{
    const float* hs    = (const float*)d_in[0];
    const float* mask  = (const float*)d_in[1];
    const float* Wq    = (const float*)d_in[2];
    const float* bq    = (const float*)d_in[3];
    const float* Wk    = (const float*)d_in[4];
    const float* bk    = (const float*)d_in[5];
    const float* Wv    = (const float*)d_in[6];
    const float* bv    = (const float*)d_in[7];
    const float* Wo    = (const float*)d_in[8];
    const float* bo    = (const float*)d_in[9];
    const float* omega = (const float*)d_in[10];
    const float* rffb  = (const float*)d_in[11];
    float* out = (float*)d_out;

    short* wsS = (short*)d_ws;
    short* hsb = wsS;                       // 2,097,152
    short* wqb = hsb + 2097152;             // 1,048,576
    short* wkb = wqb + 1048576;
    short* wvb = wkb + 1048576;
    short* wob = wvb + 1048576;
    short* qb  = wob + 1048576;             // 2,097,152
    short* kb  = qb  + 2097152;
    short* vtb = kb  + 2097152;             // 2,097,152  [h][d][s]
    short* ctxb= vtb + 2097152;             // 2,097,152
    short* QaB = ctxb+ 2097152;             // 6,291,456  [h][s][192]
    short* KaB = QaB + 6291456;

    conv_kernel<<<6144, 256, 0, stream>>>(hs, Wq, Wk, Wv, Wo, hsb, wqb, wkb, wvb, wob);
    gemm_mfma<<<dim3(8, 16, 3), 256, 0, stream>>>(hsb, wqb, bq, qb, wkb, bk, kb, wvb, bv, vtb,
                                                  0, 0, 1, S_LEN);
    phi_kernel<<<4096, 256, 0, stream>>>(qb, kb, omega, rffb, QaB, KaB);
    flash_mfma<<<dim3(16, 16), 256, 0, stream>>>(QaB, KaB, vtb, mask, ctxb);
    gemm_mfma<<<dim3(8, 16, 1), 256, 0, stream>>>(ctxb, wob, bo, out, wob, bo, out, wob, bo, out,
                                                  2, 2, 2, S_LEN);
}

// Round 3
// 159.805 us; speedup vs baseline: 5.7893x; 1.4665x over previous
//
#include <hip/hip_runtime.h>
#include <math.h>

#define S_LEN 2048
#define HID   1024
#define NH    16
#define HD    64
#define NM    128
#define CAUG  192
#define KC    64
#define NT    (S_LEN / KC)

constexpr float ALPHA = 0.9f;

typedef __attribute__((ext_vector_type(8))) short bf16x8;
typedef __attribute__((ext_vector_type(4))) short bf16x4;
typedef __attribute__((ext_vector_type(4))) float f32x4;
typedef __attribute__((ext_vector_type(4))) int   int4v;

#define MFMA(a,b,c) __builtin_amdgcn_mfma_f32_16x16x32_bf16(a,b,c,0,0,0)

static __device__ inline short f2bf(float f) {
    unsigned u = __float_as_uint(f);
    u += 0x7fffu + ((u >> 16) & 1u);      // RNE
    return (short)(u >> 16);
}
static __device__ inline float bf2f(short s) {
    return __uint_as_float(((unsigned)(unsigned short)s) << 16);
}

// ---------------------------------------------------------------------------
// fp32 -> bf16 conversion: hs (2M elems) + Wq/Wk/Wv/Wo (1M each), float4-wide
// ---------------------------------------------------------------------------
__global__ __launch_bounds__(256)
void conv_kernel(const float* __restrict__ hs,
                 const float* __restrict__ Wq, const float* __restrict__ Wk,
                 const float* __restrict__ Wv, const float* __restrict__ Wo,
                 short* __restrict__ hsb, short* __restrict__ wqb, short* __restrict__ wkb,
                 short* __restrict__ wvb, short* __restrict__ wob)
{
    int i = blockIdx.x * 256 + threadIdx.x;           // f4-unit index, 1,572,864 total
    if (i >= 1572864) return;
    const float* src; short* dst; int off;
    if (i < 524288) { src = hs; dst = hsb; off = i; }
    else {
        int j = i - 524288;
        int r = j >> 18;              // 0..3
        off = j & 262143;
        src = (r == 0) ? Wq : (r == 1) ? Wk : (r == 2) ? Wv : Wo;
        dst = (r == 0) ? wqb : (r == 1) ? wkb : (r == 2) ? wvb : wob;
    }
    float4 v = ((const float4*)src)[off];
    bf16x4 o; o[0] = f2bf(v.x); o[1] = f2bf(v.y); o[2] = f2bf(v.z); o[3] = f2bf(v.w);
    ((bf16x4*)dst)[off] = o;
}

// ---------------------------------------------------------------------------
// omega f32 [h][d][m] -> bf16 transposed om_t [h][m][d]
// ---------------------------------------------------------------------------
__global__ __launch_bounds__(256)
void omt_kernel(const float* __restrict__ omega, short* __restrict__ omtb)
{
    int i = blockIdx.x * 256 + threadIdx.x;   // 131072 = 16*64*128
    if (i >= 131072) return;
    int h = i >> 13, rem = i & 8191;
    int d = rem >> 7, m = rem & 127;
    omtb[((h * 128 + m) << 6) + d] = f2bf(omega[i]);
}

// ---------------------------------------------------------------------------
// bf16 MFMA GEMM: C = A(2048x1024) @ W(1024x1024)^T + bias
// mode 0: C bf16 [m][1024];  mode 1: C bf16 transposed [n][Mrows];  mode 2: C f32
// ---------------------------------------------------------------------------
__global__ __launch_bounds__(256)
void gemm_mfma(const short* __restrict__ A,
               const short* __restrict__ W0, const float* __restrict__ b0, void* C0,
               const short* __restrict__ W1, const float* __restrict__ b1, void* C1,
               const short* __restrict__ W2, const float* __restrict__ b2, void* C2,
               int m0_, int m1_, int m2_, int Mrows)
{
    const short* W; const float* bias; void* C; int mode;
    if (blockIdx.z == 0)      { W = W0; bias = b0; C = C0; mode = m0_; }
    else if (blockIdx.z == 1) { W = W1; bias = b1; C = C1; mode = m1_; }
    else                      { W = W2; bias = b2; C = C2; mode = m2_; }

    __shared__ short As[128][40];
    __shared__ short Bs[128][40];

    const int tid = threadIdx.x;
    const int wave = tid >> 6, lane = tid & 63;
    const int l15 = lane & 15, l4 = lane >> 4;
    const int wm = wave >> 1, wn = wave & 1;
    const int m0 = blockIdx.y * 128, n0 = blockIdx.x * 128;

    const int srow = (tid >> 2);
    const int scol = (tid & 3) * 16;

    f32x4 acc[4][4];
#pragma unroll
    for (int i = 0; i < 4; ++i)
#pragma unroll
        for (int j = 0; j < 4; ++j) acc[i][j] = (f32x4){0.f,0.f,0.f,0.f};

    int4v apre[2], bpre[2];
#pragma unroll
    for (int it = 0; it < 2; ++it) {
        apre[it] = *(const int4v*)((const char*)A + (size_t)(m0 + srow + it*64) * 2048 + scol);
        bpre[it] = *(const int4v*)((const char*)W + (size_t)(n0 + srow + it*64) * 2048 + scol);
    }

    for (int ks = 0; ks < 32; ++ks) {
        __syncthreads();
#pragma unroll
        for (int it = 0; it < 2; ++it) {
            *(int4v*)((char*)&As[0][0] + (srow + it*64) * 80 + scol) = apre[it];
            *(int4v*)((char*)&Bs[0][0] + (srow + it*64) * 80 + scol) = bpre[it];
        }
        __syncthreads();
        if (ks + 1 < 32) {
            const int kb = (ks + 1) * 64;
#pragma unroll
            for (int it = 0; it < 2; ++it) {
                apre[it] = *(const int4v*)((const char*)A + (size_t)(m0 + srow + it*64) * 2048 + kb + scol);
                bpre[it] = *(const int4v*)((const char*)W + (size_t)(n0 + srow + it*64) * 2048 + kb + scol);
            }
        }
        bf16x8 af[4], bf[4];
#pragma unroll
        for (int mi = 0; mi < 4; ++mi)
            af[mi] = *(const bf16x8*)((const char*)&As[0][0] + (wm*64 + mi*16 + l15) * 80 + l4*16);
#pragma unroll
        for (int nj = 0; nj < 4; ++nj)
            bf[nj] = *(const bf16x8*)((const char*)&Bs[0][0] + (wn*64 + nj*16 + l15) * 80 + l4*16);
#pragma unroll
        for (int mi = 0; mi < 4; ++mi)
#pragma unroll
            for (int nj = 0; nj < 4; ++nj)
                acc[mi][nj] = MFMA(af[mi], bf[nj], acc[mi][nj]);
    }

#pragma unroll
    for (int nj = 0; nj < 4; ++nj) {
        const int nglob = n0 + wn*64 + nj*16 + l15;
        const float bn = bias[nglob];
#pragma unroll
        for (int mi = 0; mi < 4; ++mi) {
            const int mbase = m0 + wm*64 + mi*16 + l4*4;
            if (mode == 0) {
#pragma unroll
                for (int r = 0; r < 4; ++r)
                    ((short*)C)[(size_t)(mbase + r) * 1024 + nglob] = f2bf(acc[mi][nj][r] + bn);
            } else if (mode == 1) {
                bf16x4 pk;
#pragma unroll
                for (int r = 0; r < 4; ++r) pk[r] = f2bf(acc[mi][nj][r] + bn);
                *(bf16x4*)((short*)C + (size_t)nglob * Mrows + mbase) = pk;
            } else {
#pragma unroll
                for (int r = 0; r < 4; ++r)
                    ((float*)C)[(size_t)(mbase + r) * 1024 + nglob] = acc[mi][nj][r] + bn;
            }
        }
    }
}

// ---------------------------------------------------------------------------
// phi2 (MFMA): per block = one (src, head, 64 s-rows)
//  A = row-normalized q/k fragments (norm computed in-register),
//  B = om_t rows from LDS;  proj = A.B^T;  epilogue: +rff_b, cos, m-norm, store
//  Also writes the q/k part of the augmented rows.
// ---------------------------------------------------------------------------
__global__ __launch_bounds__(256)
void phi2_kernel(const short* __restrict__ qbuf, const short* __restrict__ kbuf,
                 const short* __restrict__ omtb, const float* __restrict__ rffb,
                 short* __restrict__ Qa, short* __restrict__ Ka)
{
    __shared__ short om[128][72];    // 64 d + 8 pad -> 144B rows
    __shared__ float bsh[128];

    const int src = blockIdx.z, h = blockIdx.y;
    const int s0 = blockIdx.x * 64;
    const short* X = src ? kbuf : qbuf;
    short* Out     = src ? Ka : Qa;
    const float fq   = src ? 1.0f : (ALPHA * 0.125f);
    const float fphi = src ? 1.0f : ((1.0f - ALPHA) * 0.125f);

    const int tid = threadIdx.x, wave = tid >> 6, lane = tid & 63;
    const int l15 = lane & 15, l4 = lane >> 4;

    {
        const char* gsrc = (const char*)(omtb + ((size_t)h << 13));
#pragma unroll
        for (int it = 0; it < 4; ++it) {
            int f = tid * 16 + it * 4096;
            int row = f >> 7, colb = f & 127;
            *(int4v*)((char*)&om[0][0] + row * 144 + colb) = *(const int4v*)(gsrc + f);
        }
        if (tid < 128) bsh[tid] = rffb[h * 128 + tid];
    }
    __syncthreads();

    const int srow = s0 + wave * 16 + l15;

    // load x fragments (A layout: row=l15, k=cs*32+l4*8)
    bf16x8 xf[2];
#pragma unroll
    for (int cs = 0; cs < 2; ++cs)
        xf[cs] = *(const bf16x8*)(X + (size_t)srow * HID + h * HD + cs * 32 + l4 * 8);

    float ss = 0.f;
#pragma unroll
    for (int cs = 0; cs < 2; ++cs)
#pragma unroll
        for (int j = 0; j < 8; ++j) { float v = bf2f(xf[cs][j]); ss = fmaf(v, v, ss); }
    ss += __shfl_xor(ss, 16);
    ss += __shfl_xor(ss, 32);
    const float inv = 1.0f / (sqrtf(ss) + 1e-6f);

    bf16x8 qn[2];
#pragma unroll
    for (int cs = 0; cs < 2; ++cs) {
        bf16x8 o, w;
#pragma unroll
        for (int j = 0; j < 8; ++j) {
            float v = bf2f(xf[cs][j]);
            o[j] = f2bf(v * inv);
            w[j] = f2bf(v * fq);
        }
        qn[cs] = o;
        *(bf16x8*)(Out + ((size_t)h * S_LEN + srow) * CAUG + cs * 32 + l4 * 8) = w;
    }

    // proj[s][m] = qn . om_t^T
    f32x4 pacc[8];
#pragma unroll
    for (int t = 0; t < 8; ++t) pacc[t] = (f32x4){0.f,0.f,0.f,0.f};
#pragma unroll
    for (int t = 0; t < 8; ++t)
#pragma unroll
        for (int cs = 0; cs < 2; ++cs) {
            bf16x8 bf = *(const bf16x8*)((const char*)&om[0][0] + (t*16 + l15) * 144 + cs*64 + l4*16);
            pacc[t] = MFMA(qn[cs], bf, pacc[t]);
        }

    // epilogue: D layout row = l4*4+r, col m = t*16+l15
    float ph[8][4];
    float ps[4] = {0.f, 0.f, 0.f, 0.f};
#pragma unroll
    for (int t = 0; t < 8; ++t) {
        const float bv = bsh[t * 16 + l15];
#pragma unroll
        for (int r = 0; r < 4; ++r) {
            float p = pacc[t][r] + bv;
            float c = 0.125f * __cosf(p);
            ph[t][r] = c;
            ps[r] = fmaf(c, c, ps[r]);
        }
    }
#pragma unroll
    for (int r = 0; r < 4; ++r) {
        ps[r] += __shfl_xor(ps[r], 1);
        ps[r] += __shfl_xor(ps[r], 2);
        ps[r] += __shfl_xor(ps[r], 4);
        ps[r] += __shfl_xor(ps[r], 8);
    }
    float inv2[4];
#pragma unroll
    for (int r = 0; r < 4; ++r) inv2[r] = fphi / (sqrtf(ps[r]) + 1e-6f);

#pragma unroll
    for (int t = 0; t < 8; ++t)
#pragma unroll
        for (int r = 0; r < 4; ++r)
            Out[((size_t)h * S_LEN + s0 + wave * 16 + l4 * 4 + r) * CAUG + 64 + t * 16 + l15]
                = f2bf(ph[t][r] * inv2[r]);
}

// ---------------------------------------------------------------------------
// MFMA flash attention (unchanged from round 2)
// ---------------------------------------------------------------------------
__global__ __launch_bounds__(256)
void flash_mfma(const short* __restrict__ Qa, const short* __restrict__ Ka,
                const short* __restrict__ vt, const float* __restrict__ mask,
                short* __restrict__ ctxb)
{
    __shared__ short Ks[64][200];
    __shared__ short Vt[64][72];
    __shared__ short Pl[4][32][72];

    const int tid = threadIdx.x;
    const int wave = tid >> 6, lane = tid & 63;
    const int l15 = lane & 15, l4 = lane >> 4;
    const int h = blockIdx.y;
    const int q0 = blockIdx.x * 128 + wave * 32;

    bf16x8 qf[2][6];
#pragma unroll
    for (int qj = 0; qj < 2; ++qj)
#pragma unroll
        for (int cs = 0; cs < 6; ++cs)
            qf[qj][cs] = *(const bf16x8*)(Qa + ((size_t)h * 2048 + q0 + qj*16 + l15) * CAUG + cs*32 + l4*8);

    f32x4 oacc[4][2];
#pragma unroll
    for (int di = 0; di < 4; ++di)
#pragma unroll
        for (int qj = 0; qj < 2; ++qj) oacc[di][qj] = (f32x4){0.f,0.f,0.f,0.f};
    float mreg[2] = {-1e30f, -1e30f}, lreg[2] = {0.f, 0.f};

    int kr[6], kcb[6], vr[2], vcb[2];
#pragma unroll
    for (int it = 0; it < 6; ++it) { int f = tid*16 + it*4096; kr[it] = f/384; kcb[it] = f%384; }
#pragma unroll
    for (int it = 0; it < 2; ++it) { int f = tid*16 + it*4096; vr[it] = f/128; vcb[it] = f%128; }

    const char* Kg = (const char*)(Ka + (size_t)h * 2048 * CAUG);
    const char* Vg = (const char*)(vt + (size_t)h * 64 * 2048);

    int4v kpre[6], vpre[2];
#pragma unroll
    for (int it = 0; it < 6; ++it) kpre[it] = *(const int4v*)(Kg + (size_t)kr[it]*384 + kcb[it]);
#pragma unroll
    for (int it = 0; it < 2; ++it) vpre[it] = *(const int4v*)(Vg + (size_t)vr[it]*4096 + vcb[it]);

    for (int kt = 0; kt < NT; ++kt) {
        __syncthreads();
#pragma unroll
        for (int it = 0; it < 6; ++it)
            *(int4v*)((char*)&Ks[0][0] + kr[it]*400 + kcb[it]) = kpre[it];
#pragma unroll
        for (int it = 0; it < 2; ++it)
            *(int4v*)((char*)&Vt[0][0] + vr[it]*144 + vcb[it]) = vpre[it];
        __syncthreads();
        if (kt + 1 < NT) {
            const size_t ko = (size_t)(kt + 1) * 64 * 384;
            const size_t vo = (size_t)(kt + 1) * 128;
#pragma unroll
            for (int it = 0; it < 6; ++it) kpre[it] = *(const int4v*)(Kg + ko + (size_t)kr[it]*384 + kcb[it]);
#pragma unroll
            for (int it = 0; it < 2; ++it) vpre[it] = *(const int4v*)(Vg + (size_t)vr[it]*4096 + vo + vcb[it]);
        }

        f32x4 sacc[4][2];
#pragma unroll
        for (int fi = 0; fi < 4; ++fi)
#pragma unroll
            for (int qj = 0; qj < 2; ++qj) sacc[fi][qj] = (f32x4){0.f,0.f,0.f,0.f};
#pragma unroll
        for (int cs = 0; cs < 6; ++cs) {
            bf16x8 ka[4];
#pragma unroll
            for (int fi = 0; fi < 4; ++fi)
                ka[fi] = *(const bf16x8*)((const char*)&Ks[0][0] + (fi*16 + l15)*400 + cs*64 + l4*16);
#pragma unroll
            for (int fi = 0; fi < 4; ++fi)
#pragma unroll
                for (int qj = 0; qj < 2; ++qj)
                    sacc[fi][qj] = MFMA(ka[fi], qf[qj][cs], sacc[fi][qj]);
        }
#pragma unroll
        for (int fi = 0; fi < 4; ++fi) {
            float4 mk = *(const float4*)&mask[kt*64 + fi*16 + l4*4];
            float mv[4] = {mk.x * -10000.f, mk.y * -10000.f, mk.z * -10000.f, mk.w * -10000.f};
#pragma unroll
            for (int qj = 0; qj < 2; ++qj)
#pragma unroll
                for (int r = 0; r < 4; ++r) sacc[fi][qj][r] += mv[r];
        }
#pragma unroll
        for (int qj = 0; qj < 2; ++qj) {
            float pm = -1e30f;
#pragma unroll
            for (int fi = 0; fi < 4; ++fi)
#pragma unroll
                for (int r = 0; r < 4; ++r) pm = fmaxf(pm, sacc[fi][qj][r]);
            pm = fmaxf(pm, __shfl_xor(pm, 16));
            pm = fmaxf(pm, __shfl_xor(pm, 32));
            const float mnew = fmaxf(mreg[qj], pm);
            const float sc = __expf(mreg[qj] - mnew);
            mreg[qj] = mnew;
            float ps = 0.f;
#pragma unroll
            for (int fi = 0; fi < 4; ++fi)
#pragma unroll
                for (int r = 0; r < 4; ++r) {
                    float p = __expf(sacc[fi][qj][r] - mnew);
                    sacc[fi][qj][r] = p;
                    ps += p;
                }
            ps += __shfl_xor(ps, 16);
            ps += __shfl_xor(ps, 32);
            lreg[qj] = lreg[qj] * sc + ps;
#pragma unroll
            for (int di = 0; di < 4; ++di)
#pragma unroll
                for (int r = 0; r < 4; ++r) oacc[di][qj][r] *= sc;
#pragma unroll
            for (int fi = 0; fi < 4; ++fi) {
                bf16x4 pk;
#pragma unroll
                for (int r = 0; r < 4; ++r) pk[r] = f2bf(sacc[fi][qj][r]);
                *(bf16x4*)(&Pl[wave][qj*16 + l15][fi*16 + l4*4]) = pk;
            }
        }
#pragma unroll
        for (int cs2 = 0; cs2 < 2; ++cs2) {
            bf16x8 va[4], pb[2];
#pragma unroll
            for (int di = 0; di < 4; ++di)
                va[di] = *(const bf16x8*)((const char*)&Vt[0][0] + (di*16 + l15)*144 + cs2*64 + l4*16);
#pragma unroll
            for (int qj = 0; qj < 2; ++qj)
                pb[qj] = *(const bf16x8*)((const char*)&Pl[wave][0][0] + (qj*16 + l15)*144 + cs2*64 + l4*16);
#pragma unroll
            for (int di = 0; di < 4; ++di)
#pragma unroll
                for (int qj = 0; qj < 2; ++qj)
                    oacc[di][qj] = MFMA(va[di], pb[qj], oacc[di][qj]);
        }
    }

#pragma unroll
    for (int qj = 0; qj < 2; ++qj) {
        const float inv = 1.0f / lreg[qj];
        const int s = q0 + qj*16 + l15;
#pragma unroll
        for (int di = 0; di < 4; ++di) {
            bf16x4 o;
#pragma unroll
            for (int r = 0; r < 4; ++r) o[r] = f2bf(oacc[di][qj][r] * inv);
            *(bf16x4*)(ctxb + (size_t)s * HID + h*64 + di*16 + l4*4) = o;
        }
    }
}

// ---------------------------------------------------------------------------
extern "C" void kernel_launch(void* const* d_in, const int* in_sizes, int n_in,
                              void* d_out, int out_size, void* d_ws, size_t ws_size,
                              hipStream_t stream)
{
    const float* hs    = (const float*)d_in[0];
    const float* mask  = (const float*)d_in[1];
    const float* Wq    = (const float*)d_in[2];
    const float* bq    = (const float*)d_in[3];
    const float* Wk    = (const float*)d_in[4];
    const float* bk    = (const float*)d_in[5];
    const float* Wv    = (const float*)d_in[6];
    const float* bv    = (const float*)d_in[7];
    const float* Wo    = (const float*)d_in[8];
    const float* bo    = (const float*)d_in[9];
    const float* omega = (const float*)d_in[10];
    const float* rffb  = (const float*)d_in[11];
    float* out = (float*)d_out;

    short* wsS = (short*)d_ws;
    short* hsb = wsS;                       // 2,097,152
    short* wqb = hsb + 2097152;             // 1,048,576
    short* wkb = wqb + 1048576;
    short* wvb = wkb + 1048576;
    short* wob = wvb + 1048576;
    short* qb  = wob + 1048576;             // 2,097,152
    short* kb  = qb  + 2097152;
    short* vtb = kb  + 2097152;             // 2,097,152  [h][d][s]
    short* ctxb= vtb + 2097152;             // 2,097,152
    short* QaB = ctxb+ 2097152;             // 6,291,456  [h][s][192]
    short* KaB = QaB + 6291456;
    short* omtb= KaB + 6291456;             // 131,072    [h][m][d]

    conv_kernel<<<6144, 256, 0, stream>>>(hs, Wq, Wk, Wv, Wo, hsb, wqb, wkb, wvb, wob);
    omt_kernel<<<512, 256, 0, stream>>>(omega, omtb);
    gemm_mfma<<<dim3(8, 16, 3), 256, 0, stream>>>(hsb, wqb, bq, qb, wkb, bk, kb, wvb, bv, vtb,
                                                  0, 0, 1, S_LEN);
    phi2_kernel<<<dim3(32, 16, 2), 256, 0, stream>>>(qb, kb, omtb, rffb, QaB, KaB);
    flash_mfma<<<dim3(16, 16), 256, 0, stream>>>(QaB, KaB, vtb, mask, ctxb);
    gemm_mfma<<<dim3(8, 16, 1), 256, 0, stream>>>(ctxb, wob, bo, out, wob, bo, out, wob, bo, out,
                                                  2, 2, 2, S_LEN);
}

// Round 4
// 140.832 us; speedup vs baseline: 6.5692x; 1.1347x over previous
//
#include <hip/hip_runtime.h>
#include <math.h>

#define S_LEN 2048
#define HID   1024
#define NH    16
#define HD    64
#define NM    128
#define CAUG  192
#define KC    64
#define NT    (S_LEN / KC)

constexpr float ALPHA = 0.9f;

typedef __attribute__((ext_vector_type(8))) short bf16x8;
typedef __attribute__((ext_vector_type(4))) short bf16x4;
typedef __attribute__((ext_vector_type(4))) float f32x4;
typedef __attribute__((ext_vector_type(4))) int   int4v;

#define MFMA(a,b,c) __builtin_amdgcn_mfma_f32_16x16x32_bf16(a,b,c,0,0,0)

static __device__ inline short f2bf(float f) {
    unsigned u = __float_as_uint(f);
    u += 0x7fffu + ((u >> 16) & 1u);      // RNE
    return (short)(u >> 16);
}
static __device__ inline float bf2f(short s) {
    return __uint_as_float(((unsigned)(unsigned short)s) << 16);
}

// ---------------------------------------------------------------------------
// fp32 -> bf16 conversion: hs + 4 weights, float4-wide; tail range does the
// omega [h][d][m] -> om_t bf16 [h][m][d] transpose (scalar scatter, small).
// ---------------------------------------------------------------------------
__global__ __launch_bounds__(256)
void conv_kernel(const float* __restrict__ hs,
                 const float* __restrict__ Wq, const float* __restrict__ Wk,
                 const float* __restrict__ Wv, const float* __restrict__ Wo,
                 const float* __restrict__ omega,
                 short* __restrict__ hsb, short* __restrict__ wqb, short* __restrict__ wkb,
                 short* __restrict__ wvb, short* __restrict__ wob, short* __restrict__ omtb)
{
    int i = blockIdx.x * 256 + threadIdx.x;           // f4-unit index
    if (i >= 1605632) return;
    if (i >= 1572864) {                               // omega transpose tail
        int j = (i - 1572864) * 4;                    // elem index in [h][d][m]
        int h = j >> 13, rem = j & 8191;
        int d = rem >> 7, m = rem & 127;
        float4 v = *(const float4*)(omega + j);       // 4 consecutive m
        short* dst = omtb + ((h * 128 + m) << 6) + d; // [h][m][d]
        dst[0]       = f2bf(v.x);
        dst[64]      = f2bf(v.y);
        dst[128]     = f2bf(v.z);
        dst[192]     = f2bf(v.w);
        return;
    }
    const float* src; short* dst; int off;
    if (i < 524288) { src = hs; dst = hsb; off = i; }
    else {
        int j = i - 524288;
        int r = j >> 18;              // 0..3
        off = j & 262143;
        src = (r == 0) ? Wq : (r == 1) ? Wk : (r == 2) ? Wv : Wo;
        dst = (r == 0) ? wqb : (r == 1) ? wkb : (r == 2) ? wvb : wob;
    }
    float4 v = ((const float4*)src)[off];
    bf16x4 o; o[0] = f2bf(v.x); o[1] = f2bf(v.y); o[2] = f2bf(v.z); o[3] = f2bf(v.w);
    ((bf16x4*)dst)[off] = o;
}

// ---------------------------------------------------------------------------
// bf16 MFMA GEMM: C = A(2048x1024) @ W(1024x1024)^T + bias
// mode 0: C bf16 [m][1024];  mode 1: C bf16 transposed [n][Mrows];  mode 2: C f32
// ---------------------------------------------------------------------------
__global__ __launch_bounds__(256)
void gemm_mfma(const short* __restrict__ A,
               const short* __restrict__ W0, const float* __restrict__ b0, void* C0,
               const short* __restrict__ W1, const float* __restrict__ b1, void* C1,
               const short* __restrict__ W2, const float* __restrict__ b2, void* C2,
               int m0_, int m1_, int m2_, int Mrows)
{
    const short* W; const float* bias; void* C; int mode;
    if (blockIdx.z == 0)      { W = W0; bias = b0; C = C0; mode = m0_; }
    else if (blockIdx.z == 1) { W = W1; bias = b1; C = C1; mode = m1_; }
    else                      { W = W2; bias = b2; C = C2; mode = m2_; }

    __shared__ short As[128][40];
    __shared__ short Bs[128][40];

    const int tid = threadIdx.x;
    const int wave = tid >> 6, lane = tid & 63;
    const int l15 = lane & 15, l4 = lane >> 4;
    const int wm = wave >> 1, wn = wave & 1;
    const int m0 = blockIdx.y * 128, n0 = blockIdx.x * 128;

    const int srow = (tid >> 2);
    const int scol = (tid & 3) * 16;

    f32x4 acc[4][4];
#pragma unroll
    for (int i = 0; i < 4; ++i)
#pragma unroll
        for (int j = 0; j < 4; ++j) acc[i][j] = (f32x4){0.f,0.f,0.f,0.f};

    int4v apre[2], bpre[2];
#pragma unroll
    for (int it = 0; it < 2; ++it) {
        apre[it] = *(const int4v*)((const char*)A + (size_t)(m0 + srow + it*64) * 2048 + scol);
        bpre[it] = *(const int4v*)((const char*)W + (size_t)(n0 + srow + it*64) * 2048 + scol);
    }

    for (int ks = 0; ks < 32; ++ks) {
        __syncthreads();
#pragma unroll
        for (int it = 0; it < 2; ++it) {
            *(int4v*)((char*)&As[0][0] + (srow + it*64) * 80 + scol) = apre[it];
            *(int4v*)((char*)&Bs[0][0] + (srow + it*64) * 80 + scol) = bpre[it];
        }
        __syncthreads();
        if (ks + 1 < 32) {
            const int kb = (ks + 1) * 64;
#pragma unroll
            for (int it = 0; it < 2; ++it) {
                apre[it] = *(const int4v*)((const char*)A + (size_t)(m0 + srow + it*64) * 2048 + kb + scol);
                bpre[it] = *(const int4v*)((const char*)W + (size_t)(n0 + srow + it*64) * 2048 + kb + scol);
            }
        }
        bf16x8 af[4], bf[4];
#pragma unroll
        for (int mi = 0; mi < 4; ++mi)
            af[mi] = *(const bf16x8*)((const char*)&As[0][0] + (wm*64 + mi*16 + l15) * 80 + l4*16);
#pragma unroll
        for (int nj = 0; nj < 4; ++nj)
            bf[nj] = *(const bf16x8*)((const char*)&Bs[0][0] + (wn*64 + nj*16 + l15) * 80 + l4*16);
#pragma unroll
        for (int mi = 0; mi < 4; ++mi)
#pragma unroll
            for (int nj = 0; nj < 4; ++nj)
                acc[mi][nj] = MFMA(af[mi], bf[nj], acc[mi][nj]);
    }

#pragma unroll
    for (int nj = 0; nj < 4; ++nj) {
        const int nglob = n0 + wn*64 + nj*16 + l15;
        const float bn = bias[nglob];
#pragma unroll
        for (int mi = 0; mi < 4; ++mi) {
            const int mbase = m0 + wm*64 + mi*16 + l4*4;
            if (mode == 0) {
#pragma unroll
                for (int r = 0; r < 4; ++r)
                    ((short*)C)[(size_t)(mbase + r) * 1024 + nglob] = f2bf(acc[mi][nj][r] + bn);
            } else if (mode == 1) {
                bf16x4 pk;
#pragma unroll
                for (int r = 0; r < 4; ++r) pk[r] = f2bf(acc[mi][nj][r] + bn);
                *(bf16x4*)((short*)C + (size_t)nglob * Mrows + mbase) = pk;
            } else {
#pragma unroll
                for (int r = 0; r < 4; ++r)
                    ((float*)C)[(size_t)(mbase + r) * 1024 + nglob] = acc[mi][nj][r] + bn;
            }
        }
    }
}

// ---------------------------------------------------------------------------
// phi2 (MFMA): per block = one (src, head, 64 s-rows)
// ---------------------------------------------------------------------------
__global__ __launch_bounds__(256)
void phi2_kernel(const short* __restrict__ qbuf, const short* __restrict__ kbuf,
                 const short* __restrict__ omtb, const float* __restrict__ rffb,
                 short* __restrict__ Qa, short* __restrict__ Ka)
{
    __shared__ short om[128][72];
    __shared__ float bsh[128];

    const int src = blockIdx.z, h = blockIdx.y;
    const int s0 = blockIdx.x * 64;
    const short* X = src ? kbuf : qbuf;
    short* Out     = src ? Ka : Qa;
    const float fq   = src ? 1.0f : (ALPHA * 0.125f);
    const float fphi = src ? 1.0f : ((1.0f - ALPHA) * 0.125f);

    const int tid = threadIdx.x, wave = tid >> 6, lane = tid & 63;
    const int l15 = lane & 15, l4 = lane >> 4;

    {
        const char* gsrc = (const char*)(omtb + ((size_t)h << 13));
#pragma unroll
        for (int it = 0; it < 4; ++it) {
            int f = tid * 16 + it * 4096;
            int row = f >> 7, colb = f & 127;
            *(int4v*)((char*)&om[0][0] + row * 144 + colb) = *(const int4v*)(gsrc + f);
        }
        if (tid < 128) bsh[tid] = rffb[h * 128 + tid];
    }
    __syncthreads();

    const int srow = s0 + wave * 16 + l15;

    bf16x8 xf[2];
#pragma unroll
    for (int cs = 0; cs < 2; ++cs)
        xf[cs] = *(const bf16x8*)(X + (size_t)srow * HID + h * HD + cs * 32 + l4 * 8);

    float ss = 0.f;
#pragma unroll
    for (int cs = 0; cs < 2; ++cs)
#pragma unroll
        for (int j = 0; j < 8; ++j) { float v = bf2f(xf[cs][j]); ss = fmaf(v, v, ss); }
    ss += __shfl_xor(ss, 16);
    ss += __shfl_xor(ss, 32);
    const float inv = 1.0f / (sqrtf(ss) + 1e-6f);

    bf16x8 qn[2];
#pragma unroll
    for (int cs = 0; cs < 2; ++cs) {
        bf16x8 o, w;
#pragma unroll
        for (int j = 0; j < 8; ++j) {
            float v = bf2f(xf[cs][j]);
            o[j] = f2bf(v * inv);
            w[j] = f2bf(v * fq);
        }
        qn[cs] = o;
        *(bf16x8*)(Out + ((size_t)h * S_LEN + srow) * CAUG + cs * 32 + l4 * 8) = w;
    }

    f32x4 pacc[8];
#pragma unroll
    for (int t = 0; t < 8; ++t) pacc[t] = (f32x4){0.f,0.f,0.f,0.f};
#pragma unroll
    for (int t = 0; t < 8; ++t)
#pragma unroll
        for (int cs = 0; cs < 2; ++cs) {
            bf16x8 bf = *(const bf16x8*)((const char*)&om[0][0] + (t*16 + l15) * 144 + cs*64 + l4*16);
            pacc[t] = MFMA(qn[cs], bf, pacc[t]);
        }

    float ph[8][4];
    float ps[4] = {0.f, 0.f, 0.f, 0.f};
#pragma unroll
    for (int t = 0; t < 8; ++t) {
        const float bv = bsh[t * 16 + l15];
#pragma unroll
        for (int r = 0; r < 4; ++r) {
            float p = pacc[t][r] + bv;
            float c = 0.125f * __cosf(p);
            ph[t][r] = c;
            ps[r] = fmaf(c, c, ps[r]);
        }
    }
#pragma unroll
    for (int r = 0; r < 4; ++r) {
        ps[r] += __shfl_xor(ps[r], 1);
        ps[r] += __shfl_xor(ps[r], 2);
        ps[r] += __shfl_xor(ps[r], 4);
        ps[r] += __shfl_xor(ps[r], 8);
    }
    float inv2[4];
#pragma unroll
    for (int r = 0; r < 4; ++r) inv2[r] = fphi / (sqrtf(ps[r]) + 1e-6f);

#pragma unroll
    for (int t = 0; t < 8; ++t)
#pragma unroll
        for (int r = 0; r < 4; ++r)
            Out[((size_t)h * S_LEN + s0 + wave * 16 + l4 * 4 + r) * CAUG + 64 + t * 16 + l15]
                = f2bf(ph[t][r] * inv2[r]);
}

// ---------------------------------------------------------------------------
// MFMA flash attention.  q-tile 64 (wave owns 16 q-rows), grid 32x16 = 512
// blocks -> 2 blocks/CU co-resident: one block computes while the other sits
// in its staging barrier.
// ---------------------------------------------------------------------------
__global__ __launch_bounds__(256)
void flash_mfma(const short* __restrict__ Qa, const short* __restrict__ Ka,
                const short* __restrict__ vt, const float* __restrict__ mask,
                short* __restrict__ ctxb)
{
    __shared__ short Ks[64][200];      // 192 + 8 pad
    __shared__ short Vt[64][72];       // 64 + 8 pad
    __shared__ short Pl[4][16][72];    // per-wave private P (16 q rows)

    const int tid = threadIdx.x;
    const int wave = tid >> 6, lane = tid & 63;
    const int l15 = lane & 15, l4 = lane >> 4;
    const int h = blockIdx.y;
    const int q0 = blockIdx.x * 64 + wave * 16;

    // Q' fragments, resident whole kernel (16 q-rows)
    bf16x8 qf[6];
#pragma unroll
    for (int cs = 0; cs < 6; ++cs)
        qf[cs] = *(const bf16x8*)(Qa + ((size_t)h * 2048 + q0 + l15) * CAUG + cs*32 + l4*8);

    f32x4 oacc[4];
#pragma unroll
    for (int di = 0; di < 4; ++di) oacc[di] = (f32x4){0.f,0.f,0.f,0.f};
    float mreg = -1e30f, lreg = 0.f;

    int kr[6], kcb[6], vr[2], vcb[2];
#pragma unroll
    for (int it = 0; it < 6; ++it) { int f = tid*16 + it*4096; kr[it] = f/384; kcb[it] = f%384; }
#pragma unroll
    for (int it = 0; it < 2; ++it) { int f = tid*16 + it*4096; vr[it] = f/128; vcb[it] = f%128; }

    const char* Kg = (const char*)(Ka + (size_t)h * 2048 * CAUG);
    const char* Vg = (const char*)(vt + (size_t)h * 64 * 2048);

    int4v kpre[6], vpre[2];
#pragma unroll
    for (int it = 0; it < 6; ++it) kpre[it] = *(const int4v*)(Kg + (size_t)kr[it]*384 + kcb[it]);
#pragma unroll
    for (int it = 0; it < 2; ++it) vpre[it] = *(const int4v*)(Vg + (size_t)vr[it]*4096 + vcb[it]);

    for (int kt = 0; kt < NT; ++kt) {
        __syncthreads();
#pragma unroll
        for (int it = 0; it < 6; ++it)
            *(int4v*)((char*)&Ks[0][0] + kr[it]*400 + kcb[it]) = kpre[it];
#pragma unroll
        for (int it = 0; it < 2; ++it)
            *(int4v*)((char*)&Vt[0][0] + vr[it]*144 + vcb[it]) = vpre[it];
        __syncthreads();
        if (kt + 1 < NT) {
            const size_t ko = (size_t)(kt + 1) * 64 * 384;
            const size_t vo = (size_t)(kt + 1) * 128;
#pragma unroll
            for (int it = 0; it < 6; ++it) kpre[it] = *(const int4v*)(Kg + ko + (size_t)kr[it]*384 + kcb[it]);
#pragma unroll
            for (int it = 0; it < 2; ++it) vpre[it] = *(const int4v*)(Vg + (size_t)vr[it]*4096 + vo + vcb[it]);
        }

        // ---- scores S^T (64 kpos x 16 q) ----
        f32x4 sacc[4];
#pragma unroll
        for (int fi = 0; fi < 4; ++fi) sacc[fi] = (f32x4){0.f,0.f,0.f,0.f};
#pragma unroll
        for (int cs = 0; cs < 6; ++cs) {
            bf16x8 ka[4];
#pragma unroll
            for (int fi = 0; fi < 4; ++fi)
                ka[fi] = *(const bf16x8*)((const char*)&Ks[0][0] + (fi*16 + l15)*400 + cs*64 + l4*16);
#pragma unroll
            for (int fi = 0; fi < 4; ++fi)
                sacc[fi] = MFMA(ka[fi], qf[cs], sacc[fi]);
        }
        // mask (kpos = frag row)
#pragma unroll
        for (int fi = 0; fi < 4; ++fi) {
            float4 mk = *(const float4*)&mask[kt*64 + fi*16 + l4*4];
#pragma unroll
            for (int r = 0; r < 4; ++r)
                sacc[fi][r] += ((const float*)&mk)[r] * -10000.f;
        }
        // ---- online softmax per q-column ----
        {
            float pm = -1e30f;
#pragma unroll
            for (int fi = 0; fi < 4; ++fi)
#pragma unroll
                for (int r = 0; r < 4; ++r) pm = fmaxf(pm, sacc[fi][r]);
            pm = fmaxf(pm, __shfl_xor(pm, 16));
            pm = fmaxf(pm, __shfl_xor(pm, 32));
            const float mnew = fmaxf(mreg, pm);
            const float sc = __expf(mreg - mnew);
            mreg = mnew;
            float ps = 0.f;
#pragma unroll
            for (int fi = 0; fi < 4; ++fi)
#pragma unroll
                for (int r = 0; r < 4; ++r) {
                    float p = __expf(sacc[fi][r] - mnew);
                    sacc[fi][r] = p;
                    ps += p;
                }
            ps += __shfl_xor(ps, 16);
            ps += __shfl_xor(ps, 32);
            lreg = lreg * sc + ps;
#pragma unroll
            for (int di = 0; di < 4; ++di)
#pragma unroll
                for (int r = 0; r < 4; ++r) oacc[di][r] *= sc;
#pragma unroll
            for (int fi = 0; fi < 4; ++fi) {
                bf16x4 pk;
#pragma unroll
                for (int r = 0; r < 4; ++r) pk[r] = f2bf(sacc[fi][r]);
                *(bf16x4*)(&Pl[wave][l15][fi*16 + l4*4]) = pk;
            }
        }
        // ---- PV: O^T += V^T . P^T ----
#pragma unroll
        for (int cs2 = 0; cs2 < 2; ++cs2) {
            bf16x8 va[4], pb;
#pragma unroll
            for (int di = 0; di < 4; ++di)
                va[di] = *(const bf16x8*)((const char*)&Vt[0][0] + (di*16 + l15)*144 + cs2*64 + l4*16);
            pb = *(const bf16x8*)((const char*)&Pl[wave][0][0] + l15*144 + cs2*64 + l4*16);
#pragma unroll
            for (int di = 0; di < 4; ++di)
                oacc[di] = MFMA(va[di], pb, oacc[di]);
        }
    }

    // epilogue: ctx bf16 [s][1024]
    {
        const float inv = 1.0f / lreg;
        const int s = q0 + l15;
#pragma unroll
        for (int di = 0; di < 4; ++di) {
            bf16x4 o;
#pragma unroll
            for (int r = 0; r < 4; ++r) o[r] = f2bf(oacc[di][r] * inv);
            *(bf16x4*)(ctxb + (size_t)s * HID + h*64 + di*16 + l4*4) = o;
        }
    }
}

// ---------------------------------------------------------------------------
extern "C" void kernel_launch(void* const* d_in, const int* in_sizes, int n_in,
                              void* d_out, int out_size, void* d_ws, size_t ws_size,
                              hipStream_t stream)
{
    const float* hs    = (const float*)d_in[0];
    const float* mask  = (const float*)d_in[1];
    const float* Wq    = (const float*)d_in[2];
    const float* bq    = (const float*)d_in[3];
    const float* Wk    = (const float*)d_in[4];
    const float* bk    = (const float*)d_in[5];
    const float* Wv    = (const float*)d_in[6];
    const float* bv    = (const float*)d_in[7];
    const float* Wo    = (const float*)d_in[8];
    const float* bo    = (const float*)d_in[9];
    const float* omega = (const float*)d_in[10];
    const float* rffb  = (const float*)d_in[11];
    float* out = (float*)d_out;

    short* wsS = (short*)d_ws;
    short* hsb = wsS;                       // 2,097,152
    short* wqb = hsb + 2097152;             // 1,048,576
    short* wkb = wqb + 1048576;
    short* wvb = wkb + 1048576;
    short* wob = wvb + 1048576;
    short* qb  = wob + 1048576;             // 2,097,152
    short* kb  = qb  + 2097152;
    short* vtb = kb  + 2097152;             // 2,097,152  [h][d][s]
    short* ctxb= vtb + 2097152;             // 2,097,152
    short* QaB = ctxb+ 2097152;             // 6,291,456  [h][s][192]
    short* KaB = QaB + 6291456;
    short* omtb= KaB + 6291456;             // 131,072    [h][m][d]

    conv_kernel<<<6272, 256, 0, stream>>>(hs, Wq, Wk, Wv, Wo, omega,
                                          hsb, wqb, wkb, wvb, wob, omtb);
    gemm_mfma<<<dim3(8, 16, 3), 256, 0, stream>>>(hsb, wqb, bq, qb, wkb, bk, kb, wvb, bv, vtb,
                                                  0, 0, 1, S_LEN);
    phi2_kernel<<<dim3(32, 16, 2), 256, 0, stream>>>(qb, kb, omtb, rffb, QaB, KaB);
    flash_mfma<<<dim3(32, 16), 256, 0, stream>>>(QaB, KaB, vtb, mask, ctxb);
    gemm_mfma<<<dim3(8, 16, 1), 256, 0, stream>>>(ctxb, wob, bo, out, wob, bo, out, wob, bo, out,
                                                  2, 2, 2, S_LEN);
}